// Round 7
// baseline (141.198 us; speedup 1.0000x reference)
//
#include <hip/hip_runtime.h>
#include <stdint.h>
#include <math.h>

typedef unsigned short u16;
typedef unsigned long long ull;

// Problem constants (B=16, N=M=4096, D=3)
#define NPTS  4096
#define NB    16
#define NRES  12288               // residuals per (batch, direction)
#define NPAIR 32                  // 16 batches x 2 directions
#define G     16                  // grid cells per axis
#define NCELL 4096                // G^3
#define HCEL  0.0625f             // 1/G
#define SSTR  4160                // starts stride (u16 elems, >= 4097)
#define MARGIN 1e-5f
#define CAP   896                 // staged-candidate cap (3 slabs: mean 768, +5 sigma)
// 0-indexed order-statistic ranks for jnp.quantile(0.15/0.85, linear)
#define RANK_LO 1843u
#define RANK_HI 10443u

__device__ __forceinline__ uint32_t f2key(float f) {
    uint32_t u = __float_as_uint(f);
    return (u & 0x80000000u) ? ~u : (u | 0x80000000u);
}
__device__ __forceinline__ float key2f(uint32_t k) {
    uint32_t u = (k & 0x80000000u) ? (k ^ 0x80000000u) : ~k;
    return __uint_as_float(u);
}

// ---------------------------------------------------------------------------
// Kernel 1: build — counting-sort targets into 16^3 cells. 32 blocks x 1024.
// Zeroes this pd's histg slice; block 0 zeroes the completion counter.
// ---------------------------------------------------------------------------
__global__ __launch_bounds__(1024) void build_kernel(const float* __restrict__ x,
                                                     const float* __restrict__ y,
                                                     float4* __restrict__ arrA,
                                                     u16* __restrict__ starts,
                                                     u16* __restrict__ idx16,
                                                     uint32_t* __restrict__ histg,
                                                     unsigned int* __restrict__ counter) {
    __shared__ uint32_t hist[NCELL];          // 16 KB
    __shared__ uint32_t wpart[16];
    const int pd = blockIdx.x, b = pd >> 1, dir = pd & 1;
    const float* t = (dir == 0 ? y : x) + (size_t)b * NPTS * 3;
    const int tid = threadIdx.x, lane = tid & 63, wv = tid >> 6;

    #pragma unroll
    for (int j = 0; j < 4; ++j) hist[tid * 4 + j] = 0u;
    histg[(size_t)pd * 2048 + tid * 2 + 0] = 0u;
    histg[(size_t)pd * 2048 + tid * 2 + 1] = 0u;
    if (pd == 0 && tid == 0) counter[0] = 0u;
    __syncthreads();

    // phase 1: 4 targets/thread (12 floats = 3 aligned float4 loads)
    float f[12];
    int ci[4];
    {
        const float4* tp = reinterpret_cast<const float4*>(t + (size_t)tid * 12);
        #pragma unroll
        for (int j = 0; j < 3; ++j) {
            const float4 v = tp[j];
            f[j * 4 + 0] = v.x; f[j * 4 + 1] = v.y; f[j * 4 + 2] = v.z; f[j * 4 + 3] = v.w;
        }
        #pragma unroll
        for (int k = 0; k < 4; ++k) {
            const int cx = (int)(f[k * 3 + 0] * 16.f);
            const int cy = (int)(f[k * 3 + 1] * 16.f);
            const int cz = (int)(f[k * 3 + 2] * 16.f);
            ci[k] = (cx * G + cy) * G + cz;
            atomicAdd(&hist[ci[k]], 1u);
        }
    }
    __syncthreads();

    // phase 2: exclusive scan of 4096 bins (4/thread, 16 waves)
    {
        uint32_t loc[4], sum = 0;
        const int base = tid * 4;
        #pragma unroll
        for (int j = 0; j < 4; ++j) { loc[j] = hist[base + j]; sum += loc[j]; }
        uint32_t sc = sum;
        #pragma unroll
        for (int off = 1; off < 64; off <<= 1) {
            const uint32_t u = __shfl_up(sc, off);
            if (lane >= off) sc += u;
        }
        if (lane == 63) wpart[wv] = sc;
        __syncthreads();
        uint32_t wbase = 0;
        #pragma unroll
        for (int k = 0; k < 16; ++k) wbase += (k < wv) ? wpart[k] : 0u;
        uint32_t ex = wbase + sc - sum;
        #pragma unroll
        for (int j = 0; j < 4; ++j) { hist[base + j] = ex; ex += loc[j]; }
    }
    __syncthreads();

    // starts (exclusive prefix; entry [4096] = total)
    for (int i = tid; i <= NCELL; i += 1024)
        starts[(size_t)pd * SSTR + i] = (u16)((i == NCELL) ? NPTS : hist[i]);
    __syncthreads();

    // phase 3: scatter (order within cell arbitrary; ties use idx16)
    #pragma unroll
    for (int k = 0; k < 4; ++k) {
        const float px = f[k * 3 + 0], py = f[k * 3 + 1], pz = f[k * 3 + 2];
        const uint32_t pos = atomicAdd(&hist[ci[k]], 1u);
        const float w = fmaf(pz, pz, fmaf(py, py, px * px));
        arrA[(size_t)pd * NPTS + pos] = make_float4(-2.f * px, -2.f * py, -2.f * pz, w);
        idx16[(size_t)pd * NPTS + pos] = (u16)(tid * 4 + k);
    }
}

// ---------------------------------------------------------------------------
// Kernel 2: grid NN with LDS-staged 3-slab neighborhood.
// grid=(16 slabs x 4 subs, 32 pds) x 256 threads, 4 lanes per query.
// Queries with cx==slab are contiguous in sorted order; their full +-1-x
// neighborhood is ONE contiguous range of the sorted target array -> one
// coalesced LDS stage per block. Candidate tie field keeps GLOBAL position
// so LDS / global-fallback / shell paths are interchangeable.
// ---------------------------------------------------------------------------
__global__ __launch_bounds__(256, 8) void query_kernel(const float4* __restrict__ arrA,
                                                       const u16* __restrict__ starts,
                                                       const u16* __restrict__ idx16,
                                                       uint32_t* __restrict__ keys,
                                                       uint32_t* __restrict__ histg,
                                                       double* __restrict__ partials) {
    __shared__ float4 c4[CAP];                 // 14 KB
    __shared__ u16 cidx[CAP];                  // 1.75 KB
    __shared__ double wred[8];
    const int pd = blockIdx.y;
    const int slab = blockIdx.x >> 2, sub = blockIdx.x & 3;
    const int tid = threadIdx.x, lane = tid & 63, wv = tid >> 6, l4 = tid & 3;

    const float4* __restrict__ tp = arrA + (size_t)pd * NPTS;
    const u16* __restrict__ st = starts + (size_t)pd * SSTR;
    const u16* __restrict__ ixp = idx16 + (size_t)pd * NPTS;
    const u16* __restrict__ stq = starts + (size_t)(pd ^ 1) * SSTR;

    // stage the contiguous 3-slab candidate window
    const int wlo = st[max(slab - 1, 0) * 256];
    const int whi = st[(min(slab + 1, G - 1) + 1) * 256];
    const int wsz = whi - wlo;
    const bool useLds = (wsz <= CAP);
    if (useLds) {
        for (int i = tid; i < wsz; i += 256) { c4[i] = tp[wlo + i]; cidx[i] = ixp[wlo + i]; }
    }
    __syncthreads();

    // this sub-block's query range (queries of pd = sorted points of pd^1)
    const int qlo = stq[slab * 256], qhi = stq[(slab + 1) * 256];
    const int per = (qhi - qlo + 3) >> 2;
    const int q0 = qlo + sub * per;
    const int q1 = min(q0 + per, qhi);

    double s1 = 0.0, s2 = 0.0;

    #define SCAN_RUN_G(A_, E_)                                                      \
        for (int p2 = (A_) + l4; p2 < (E_); p2 += 4) {                              \
            const float4 T = tp[p2];                                                \
            const float d = fmaf(qx, T.x, fmaf(qy, T.y, fmaf(qz, T.z, T.w)));       \
            best = fminf(best, d);                                                  \
            const ull cand = ((ull)f2key(d) << 32) |                                \
                             ((ull)ixp[p2] << 16) | (uint32_t)p2;                   \
            pk = (cand < pk) ? cand : pk;                                           \
        }

    for (int qp = q0 + (tid >> 2); qp < q1; qp += 64) {
        const float4 Q = arrA[(size_t)(pd ^ 1) * NPTS + qp];
        const float qx = -0.5f * Q.x, qy = -0.5f * Q.y, qz = -0.5f * Q.z;
        const float qq = Q.w;                     // |q|^2 (shell bound only)
        const int cx = (int)(qx * 16.f), cy = (int)(qy * 16.f), cz = (int)(qz * 16.f);

        float best = 3.0e38f;
        ull pk = ~0ull;

        // 9 clamped z-runs (Chebyshev <=1); bounds loaded up front
        const int zlo = max(cz - 1, 0), zhi = min(cz + 1, G - 1);
        int a9[9], e9[9];
        #pragma unroll
        for (int r = 0; r < 9; ++r) {
            const int ix = min(max(cx + (r / 3) - 1, 0), G - 1);
            const int iy = min(max(cy + (r % 3) - 1, 0), G - 1);
            const int c0 = (ix * G + iy) * G;
            a9[r] = st[c0 + zlo];
            e9[r] = st[c0 + zhi + 1];
        }
        if (useLds) {
            #pragma unroll
            for (int r = 0; r < 9; ++r) {
                for (int p2 = a9[r] + l4; p2 < e9[r]; p2 += 4) {
                    const int pl = p2 - wlo;
                    const float4 T = c4[pl];
                    const float d = fmaf(qx, T.x, fmaf(qy, T.y, fmaf(qz, T.z, T.w)));
                    best = fminf(best, d);
                    const ull cand = ((ull)f2key(d) << 32) |
                                     ((ull)cidx[pl] << 16) | (uint32_t)p2;
                    pk = (cand < pk) ? cand : pk;
                }
            }
        } else {
            #pragma unroll
            for (int r = 0; r < 9; ++r) SCAN_RUN_G(a9[r], e9[r])
        }

        // expand shells (global path) while they could beat the quad's best
        for (int s = 2; s <= G - 1; ++s) {
            float qb = best;
            qb = fminf(qb, __shfl_xor(qb, 1));
            qb = fminf(qb, __shfl_xor(qb, 2));
            const float dmin = (float)(s - 1) * HCEL;
            if (fmaf(dmin, dmin, -(qb + qq)) > MARGIN) break;
            for (int dx = -s; dx <= s; ++dx) {
                const int ix = cx + dx;
                if (ix < 0 || ix > G - 1) continue;
                const int adx = dx < 0 ? -dx : dx;
                for (int dy = -s; dy <= s; ++dy) {
                    const int iy = cy + dy;
                    if (iy < 0 || iy > G - 1) continue;
                    const int ady = dy < 0 ? -dy : dy;
                    const int c0 = (ix * G + iy) * G;
                    if (max(adx, ady) == s) {     // full z range
                        const int zl = max(cz - s, 0), zh = min(cz + s, G - 1);
                        const int a = st[c0 + zl], e = st[c0 + zh + 1];
                        SCAN_RUN_G(a, e)
                    } else {                      // only z = cz +/- s
                        const int z1 = cz - s;
                        if (z1 >= 0) { const int a = st[c0 + z1], e = st[c0 + z1 + 1]; SCAN_RUN_G(a, e) }
                        const int z2 = cz + s;
                        if (z2 <= G - 1) { const int a = st[c0 + z2], e = st[c0 + z2 + 1]; SCAN_RUN_G(a, e) }
                    }
                }
            }
        }

        // quad min-reduce of packed (key, orig, global pos)
        {
            ull o = __shfl_xor(pk, 1); pk = (o < pk) ? o : pk;
            o = __shfl_xor(pk, 2);     pk = (o < pk) ? o : pk;
        }

        // residuals (exact: -0.5 * (-2t) == t bitwise)
        const int pos = (int)(pk & 0xFFFFu);
        const float4 T = tp[pos];
        const float rx = qx - (-0.5f * T.x);
        const float ry = qy - (-0.5f * T.y);
        const float rz = qz - (-0.5f * T.z);

        if (l4 < 3) {
            const uint32_t kk = (l4 == 0) ? f2key(rx) : ((l4 == 1) ? f2key(ry) : f2key(rz));
            keys[(size_t)pd * NRES + (size_t)qp * 3 + l4] = kk;
            atomicAdd(&histg[(size_t)pd * 2048 + (kk >> 21)], 1u);
        }
        if (l4 == 0) {
            s1 += (double)rx + (double)ry + (double)rz;
            s2 += (double)rx * rx + (double)ry * ry + (double)rz * rz;
        }
    }
    #undef SCAN_RUN_G

    // block reduce f64 partials
    #pragma unroll
    for (int off = 32; off; off >>= 1) { s1 += __shfl_down(s1, off); s2 += __shfl_down(s2, off); }
    if (lane == 0) { wred[wv] = s1; wred[4 + wv] = s2; }
    __syncthreads();
    if (tid == 0) {
        double a = 0.0, c = 0.0;
        for (int k = 0; k < 4; ++k) { a += wred[k]; c += wred[4 + k]; }
        partials[(size_t)pd * 128 + blockIdx.x] = a;         // s-values   [0..63]
        partials[(size_t)pd * 128 + 64 + blockIdx.x] = c;    // s2-values  [64..127]
    }
}

// ---------------------------------------------------------------------------
// Kernel 3: robust masked std + fused final reduction (last block writes out).
// 32 blocks x 512 threads; keys in registers; radix levels 2/3 in LDS.
// ---------------------------------------------------------------------------
#define STH 512

__device__ __forceinline__ void scan2048(uint32_t* h, uint32_t* wtmp) {
    const int tid = threadIdx.x, lane = tid & 63, wv = tid >> 6;
    const int i = tid * 4;
    const uint32_t a0 = h[i], a1 = h[i + 1], a2 = h[i + 2], a3 = h[i + 3];
    const uint32_t v = a0 + a1 + a2 + a3;
    uint32_t sc = v;
    #pragma unroll
    for (int off = 1; off < 64; off <<= 1) {
        const uint32_t u = __shfl_up(sc, off);
        if (lane >= off) sc += u;
    }
    if (lane == 63) wtmp[wv] = sc;
    __syncthreads();
    uint32_t base = 0;
    #pragma unroll
    for (int k = 0; k < 8; ++k) base += (k < wv) ? wtmp[k] : 0u;
    const uint32_t ex = base + sc - v;
    h[i] = ex; h[i + 1] = ex + a0; h[i + 2] = ex + a0 + a1; h[i + 3] = ex + a0 + a1 + a2;
    __syncthreads();
}

__device__ __forceinline__ int ubin(const uint32_t* cum, int n, uint32_t r) {
    int lo = 0, hi = n - 1;                    // largest b with cum[b] <= r
    while (lo < hi) {
        const int mid = (lo + hi + 1) >> 1;
        if (cum[mid] <= r) lo = mid; else hi = mid - 1;
    }
    return lo;
}

__global__ __launch_bounds__(512) void sigma_kernel(const uint32_t* __restrict__ keysg,
                                                    const uint32_t* __restrict__ histg,
                                                    const double* __restrict__ partials,
                                                    float* __restrict__ sig,
                                                    unsigned int* __restrict__ counter,
                                                    float* __restrict__ out) {
    __shared__ uint32_t hist[4096];            // 16 KB
    __shared__ uint32_t wtmp[8];
    __shared__ double dred[16];
    __shared__ int ired[16];
    __shared__ uint32_t umin[16];
    __shared__ uint32_t bc[8];
    __shared__ double sS[2];

    const int pair = blockIdx.x;
    const int tid = threadIdx.x, lane = tid & 63, wv = tid >> 6;

    // keys into registers (coalesced)
    uint32_t key[24];
    const uint32_t* kp = keysg + (size_t)pair * NRES;
    #pragma unroll
    for (int e = 0; e < 24; ++e) key[e] = kp[e * STH + tid];

    // full sums: parallel reduce of 64+64 f64 partials (waves 0 and 1)
    if (tid < 128) {
        double a = partials[(size_t)pair * 128 + tid];
        #pragma unroll
        for (int off = 32; off; off >>= 1) a += __shfl_down(a, off);
        if (lane == 0) sS[wv] = a;
    }
    __syncthreads();
    const double S = sS[0], S2 = sS[1];
    const double mu = S / NRES;
    const double var_all = (S2 - S * mu) / (NRES - 1);
    const double sd = sqrt(var_all > 0.0 ? var_all : 0.0);

    // ---- Level 1: load pre-built 11-bit histogram, scan ----
    {
        const uint32_t* hg = histg + (size_t)pair * 2048;
        #pragma unroll
        for (int j = 0; j < 4; ++j) hist[tid * 4 + j] = hg[tid * 4 + j];
    }
    __syncthreads();
    scan2048(hist, wtmp);
    if (tid < 2) {
        const uint32_t r = tid ? RANK_HI : RANK_LO;
        const int bb = ubin(hist, 2048, r);
        bc[tid * 4 + 0] = (uint32_t)bb;
        bc[tid * 4 + 1] = r - hist[bb];
    }
    __syncthreads();

    // ---- Level 2: two concurrent 11-bit histograms ----
    const uint32_t pA1 = bc[0], rA1 = bc[1], pB1 = bc[4], rB1 = bc[5];
    #pragma unroll
    for (int j = 0; j < 8; ++j) hist[tid * 8 + j] = 0u;
    __syncthreads();
    #pragma unroll
    for (int e = 0; e < 24; ++e) {
        const uint32_t k = key[e];
        const uint32_t pfx = k >> 21, bin = (k >> 10) & 2047u;
        if (pfx == pA1) atomicAdd(&hist[bin], 1u);
        if (pfx == pB1) atomicAdd(&hist[2048 + bin], 1u);
    }
    __syncthreads();
    scan2048(hist, wtmp);
    scan2048(hist + 2048, wtmp);
    if (tid < 2) {
        const uint32_t* h = hist + tid * 2048;
        const uint32_t pfx = tid ? pB1 : pA1;
        const uint32_t r = tid ? rB1 : rA1;
        const int bb = ubin(h, 2048, r);
        bc[tid * 4 + 0] = (pfx << 11) | (uint32_t)bb;
        bc[tid * 4 + 1] = r - h[bb];
    }
    __syncthreads();

    // ---- Level 3: two concurrent 10-bit histograms -> exact keys ----
    const uint32_t pA2 = bc[0], rA2 = bc[1], pB2 = bc[4], rB2 = bc[5];
    #pragma unroll
    for (int j = 0; j < 8; ++j) hist[tid * 8 + j] = 0u;
    __syncthreads();
    #pragma unroll
    for (int e = 0; e < 24; ++e) {
        const uint32_t k = key[e];
        if ((k >> 10) == pA2) atomicAdd(&hist[k & 1023u], 1u);
        if ((k >> 10) == pB2) atomicAdd(&hist[2048 + (k & 1023u)], 1u);
    }
    __syncthreads();
    scan2048(hist, wtmp);
    scan2048(hist + 2048, wtmp);
    if (tid < 2) {
        const uint32_t* h = hist + tid * 2048;
        const uint32_t pfx = tid ? pB2 : pA2;
        const uint32_t r = tid ? rB2 : rA2;
        const uint32_t rtot = tid ? RANK_HI : RANK_LO;
        const int bb = ubin(h, 1024, r);
        const uint32_t k0 = (pfx << 10) | (uint32_t)bb;
        const uint32_t abs_le = (rtot - r) + h[bb + 1];
        bc[tid * 4 + 0] = k0;
        bc[tid * 4 + 1] = (abs_le >= rtot + 2u) ? 1u : 0u;   // rank+1 shares key?
    }
    __syncthreads();

    // ---- rank+1 keys: duplicate-covered or min key strictly greater ----
    const uint32_t k0 = bc[0], dup1 = bc[1], k2 = bc[4], dup3 = bc[5];
    uint32_t m1 = 0xFFFFFFFFu, m3 = 0xFFFFFFFFu;
    #pragma unroll
    for (int e = 0; e < 24; ++e) {
        const uint32_t k = key[e];
        if (k > k0 && k < m1) m1 = k;
        if (k > k2 && k < m3) m3 = k;
    }
    {
        uint32_t a = m1, c = m3;
        #pragma unroll
        for (int off = 32; off; off >>= 1) {
            const uint32_t ua = __shfl_down(a, off), uc = __shfl_down(c, off);
            a = (ua < a) ? ua : a; c = (uc < c) ? uc : c;
        }
        if (lane == 0) { umin[wv] = a; umin[8 + wv] = c; }
    }
    __syncthreads();
    uint32_t m1r = 0xFFFFFFFFu, m3r = 0xFFFFFFFFu;
    for (int k = 0; k < 8; ++k) {
        m1r = (umin[k] < m1r) ? umin[k] : m1r;
        m3r = (umin[8 + k] < m3r) ? umin[8 + k] : m3r;
    }
    const uint32_t k1 = dup1 ? k0 : m1r;
    const uint32_t k3 = dup3 ? k2 : m3r;

    // Linear-interpolated quantiles
    const double vl0 = (double)key2f(k0), vl1 = (double)key2f(k1);
    const double vh0 = (double)key2f(k2), vh1 = (double)key2f(k3);
    const double fr_lo = 0.15 * (NRES - 1) - (double)RANK_LO;
    const double fr_hi = 0.85 * (NRES - 1) - (double)RANK_HI;
    const float q_lo = (float)(vl0 + fr_lo * (vl1 - vl0));
    const float q_hi = (float)(vh0 + fr_hi * (vh1 - vh0));

    // Pass B: counts + sums under both predicates
    int cq = 0, cs = 0;
    double sq = 0.0, ss = 0.0;
    #pragma unroll
    for (int e = 0; e < 24; ++e) {
        const float f = key2f(key[e]);
        const bool mq = (f < q_lo) || (f > q_hi);
        const bool ms = fabs((double)f - mu) > sd;
        cq += mq; cs += ms;
        if (mq) sq += f;
        if (ms) ss += f;
    }
    {
        double a = sq, c = ss;
        int ai = cq, ci = cs;
        #pragma unroll
        for (int off = 32; off; off >>= 1) {
            a += __shfl_down(a, off); c += __shfl_down(c, off);
            ai += __shfl_down(ai, off); ci += __shfl_down(ci, off);
        }
        if (lane == 0) { dred[wv] = a; dred[8 + wv] = c; ired[wv] = ai; ired[8 + wv] = ci; }
    }
    __syncthreads();
    double sq_t = 0.0, ss_t = 0.0;
    int cq_t = 0, cs_t = 0;
    for (int k = 0; k < 8; ++k) {
        sq_t += dred[k]; ss_t += dred[8 + k];
        cq_t += ired[k]; cs_t += ired[8 + k];
    }

    int mode;                 // 0 = quantile mask, 1 = simple, 2 = all
    double cnt_sel, sum_sel;
    if (cq_t > 0)      { mode = 0; cnt_sel = cq_t; sum_sel = sq_t; }
    else if (cs_t > 0) { mode = 1; cnt_sel = cs_t; sum_sel = ss_t; }
    else               { mode = 2; cnt_sel = NRES; sum_sel = S; }
    const double mean_w = sum_sel / cnt_sel;
    __syncthreads();

    // Pass C: masked unbiased variance
    double acc = 0.0;
    #pragma unroll
    for (int e = 0; e < 24; ++e) {
        const float f = key2f(key[e]);
        bool w;
        if (mode == 0)      w = (f < q_lo) || (f > q_hi);
        else if (mode == 1) w = fabs((double)f - mu) > sd;
        else                w = true;
        if (w) { const double d = (double)f - mean_w; acc += d * d; }
    }
    {
        double a = acc;
        #pragma unroll
        for (int off = 32; off; off >>= 1) a += __shfl_down(a, off);
        if (lane == 0) dred[wv] = a;
    }
    __syncthreads();
    double acc_t = 0.0;
    for (int k = 0; k < 8; ++k) acc_t += dred[k];

    // fused final: last finishing block reduces sig[] and writes out
    if (tid == 0) {
        const float sv = (float)sqrt(acc_t / (cnt_sel - 1.0));
        __hip_atomic_store(&sig[pair], sv, __ATOMIC_RELEASE, __HIP_MEMORY_SCOPE_AGENT);
        const unsigned prev = __hip_atomic_fetch_add(counter, 1u, __ATOMIC_ACQ_REL,
                                                     __HIP_MEMORY_SCOPE_AGENT);
        if (prev == NPAIR - 1) {
            float m = 0.f;
            for (int i = 0; i < NB; ++i) {
                const float s0 = __hip_atomic_load(&sig[2 * i], __ATOMIC_ACQUIRE,
                                                   __HIP_MEMORY_SCOPE_AGENT);
                const float s1 = __hip_atomic_load(&sig[2 * i + 1], __ATOMIC_ACQUIRE,
                                                   __HIP_MEMORY_SCOPE_AGENT);
                m += fmaxf(s0, s1);
            }
            out[0] = m / (float)NB;
        }
    }
}

extern "C" void kernel_launch(void* const* d_in, const int* in_sizes, int n_in,
                              void* d_out, int out_size, void* d_ws, size_t ws_size,
                              hipStream_t stream) {
    const float* x = (const float*)d_in[0];
    const float* y = (const float*)d_in[1];
    char* w = (char*)d_ws;
    float4*       arrA     = (float4*)(w);                    // 2 MB
    uint32_t*     keys     = (uint32_t*)(w + 2097152);        // 1.5 MB
    uint32_t*     histg    = (uint32_t*)(w + 3670016);        // 256 KB
    double*       partials = (double*)(w + 3932160);          // 32 KB
    float*        sig      = (float*)(w + 3964928);           // 128 B
    unsigned int* counter  = (unsigned int*)(w + 3965056);    // 128 B (padded)
    u16*          starts   = (u16*)(w + 3965184);             // 260 KB
    u16*          idx16    = (u16*)(w + 4231424);             // 256 KB

    build_kernel<<<NPAIR, 1024, 0, stream>>>(x, y, arrA, starts, idx16, histg, counter);
    query_kernel<<<dim3(64, NPAIR), 256, 0, stream>>>(arrA, starts, idx16,
                                                      keys, histg, partials);
    sigma_kernel<<<NPAIR, STH, 0, stream>>>(keys, histg, partials, sig, counter,
                                            (float*)d_out);
}